// Round 12
// baseline (178.055 us; speedup 1.0000x reference)
//
#include <hip/hip_runtime.h>

typedef __bf16 bf16x8 __attribute__((ext_vector_type(8)));
typedef __bf16 bf16x4 __attribute__((ext_vector_type(4)));
typedef float f32x4 __attribute__((ext_vector_type(4)));
typedef float f32x16 __attribute__((ext_vector_type(16)));

__device__ __forceinline__ f32x4 mfma16(bf16x8 a, bf16x8 b, f32x4 c) {
  return __builtin_amdgcn_mfma_f32_16x16x32_bf16(a, b, c, 0, 0, 0);
}
__device__ __forceinline__ f32x16 mfma32(bf16x8 a, bf16x8 b, f32x16 c) {
  return __builtin_amdgcn_mfma_f32_32x32x16_bf16(a, b, c, 0, 0, 0);
}

// pack 2 fp32 -> u32 of 2 bf16 (compiler fuses to v_cvt_pk_bf16_f32)
__device__ __forceinline__ unsigned int cvtpk(float a, float b) {
  union { __bf16 h[2]; unsigned int u; } r;
  r.h[0] = (__bf16)a; r.h[1] = (__bf16)b;
  return r.u;
}
// v_permlane32_swap_b32: exchange across the 32-lane halves
__device__ __forceinline__ void swap32(unsigned int &a, unsigned int &b) {
  asm("v_permlane32_swap_b32 %0, %1" : "+v"(a), "+v"(b));
}

// ---------------------------------------------------------------------------
// K0: convert Wf(32x256) | Wg(32x256) | Wh(256x256) fp32 -> Wb bf16 [320][256]
// ---------------------------------------------------------------------------
__global__ void wcvt_kernel(const float* __restrict__ Wf, const float* __restrict__ Wg,
                            const float* __restrict__ Wh, __bf16* __restrict__ Wb) {
  int i = blockIdx.x * 256 + threadIdx.x;  // 0..81919
  float v;
  if (i < 8192)       v = Wf[i];
  else if (i < 16384) v = Wg[i - 8192];
  else                v = Wh[i - 16384];
  Wb[i] = (__bf16)v;
}

// ---------------------------------------------------------------------------
// K1: projections.
//   o<64  -> QK_pk[b][nt(128)][qk(2)][frag(2)][h(2)][r(32)][e(8)] bf16
//   o>=64 -> V_pk[b][jc(256)][h(2)][c(256)][e(8)] bf16 (via LDS transpose)
// NEW: K features (o in [32,64)) are scaled by log2(e) at store time, so
// attn computes p = exp2(s') = e^s with raw v_exp_f32 (no per-element mul).
// ---------------------------------------------------------------------------
__global__ __launch_bounds__(512) void proj_kernel(
    const float* __restrict__ x, const float* __restrict__ bfv,
    const float* __restrict__ bgv, const float* __restrict__ bhv,
    const __bf16* __restrict__ Wb, __bf16* __restrict__ qkpk,
    __bf16* __restrict__ vpk) {
  __shared__ __align__(16) char smem[2560 + 18432];
  __bf16* xT = (__bf16*)smem;           // [32 n][40 c] bf16
  __bf16* ho = (__bf16*)(smem + 2560);  // [256 c][36 n] bf16

  const int t = threadIdx.x;
  const int l = t & 63, wg = t >> 6, q = l >> 4, l15 = l & 15;
  const int nh = wg & 1, oh = wg >> 1;   // oh 0..3
  const int bi = blockIdx.x;
  const int b = bi >> 7;
  const int nt = bi & 127;               // 32-row n tile
  const int n0 = nt << 5;

  const float* xb = x + (size_t)b * 256 * 4096;

  f32x4 acc[5];
#pragma unroll
  for (int i = 0; i < 5; i++) acc[i] = (f32x4){0.f, 0.f, 0.f, 0.f};

  const int c_rel = t >> 4;        // 0..31
  const int n2 = (t & 15) * 2;     // 0..30

#pragma unroll 1
  for (int kc = 0; kc < 8; kc++) {
    __syncthreads();
    float2 v = *(const float2*)(xb + (size_t)(kc * 32 + c_rel) * 4096 + n0 + n2);
    xT[(n2 + 0) * 40 + c_rel] = (__bf16)v.x;
    xT[(n2 + 1) * 40 + c_rel] = (__bf16)v.y;
    __syncthreads();
    bf16x8 af = *(const bf16x8*)(xT + (nh * 16 + l15) * 40 + q * 8);
    const __bf16* wp = Wb + (size_t)(oh * 80 + l15) * 256 + kc * 32 + q * 8;
#pragma unroll
    for (int ot = 0; ot < 5; ot++) {
      bf16x8 bfr = *(const bf16x8*)(wp + (size_t)ot * 16 * 256);
      acc[ot] = mfma16(af, bfr, acc[ot]);
    }
  }

#pragma unroll
  for (int ot = 0; ot < 5; ot++) {
    int o = oh * 80 + ot * 16 + l15;
    float bias = (o < 32) ? bfv[o] : (o < 64) ? bgv[o - 32] : bhv[o - 64];
    if (oh == 0 && ot < 4) {
      int qk = o >> 5, fr = (o >> 4) & 1, hh = (o >> 3) & 1, e = o & 7;
      size_t base = ((size_t)b * 128 + nt) * 2048 + qk * 1024 + fr * 512 + hh * 256;
      float sc = (o >= 32) ? 1.44269504089f : 1.0f;   // fold log2e into K
#pragma unroll
      for (int r = 0; r < 4; r++) {
        int n_rel = nh * 16 + q * 4 + r;
        qkpk[base + n_rel * 8 + e] = (__bf16)((acc[ot][r] + bias) * sc);
      }
    } else {
#pragma unroll
      for (int r = 0; r < 4; r++) {
        int n_rel = nh * 16 + q * 4 + r;
        ho[(o - 64) * 36 + n_rel] = (__bf16)(acc[ot][r] + bias);
      }
    }
  }
  __syncthreads();
  unsigned short* vpku = (unsigned short*)vpk + (size_t)b * 1048576;
  const unsigned short* hou = (const unsigned short*)ho;
  for (int e = t; e < 4096; e += 512) {
    int c = e >> 4, nn = (e & 15) * 2;
    int n = n0 + nn;
    int jc = n >> 4, hh = (n >> 3) & 1, ee = n & 7;
    unsigned int vv = *(const unsigned int*)(hou + c * 36 + nn);
    *(unsigned int*)(vpku + (((size_t)(jc * 2 + hh) * 256 + c) * 8 + ee)) = vv;
  }
}

// ---------------------------------------------------------------------------
// K2: fused attention — zero barriers, P in regs, 64i x 128c per wave.
// Grid 256 = 16 (b,jp) combos x 16 i-groups, XCD-pinned; 512 thr = 8 waves =
// 4 i-ranges(64) x 2 c-halves(128). R11 verdict: pipes ran in SEQUENCE
// (MFMA 1152 + VALU 1174 + feed 1540 ~= 3900-cyc chunk) because barriers /
// saturated L1 phase-locked the waves. Fixes here:
//  (1) V-frag REUSE: each V fragment feeds 2 MFMAs (two i-tiles) -> V feed
//      per CU-chunk 128KB -> 64KB (~1000 cyc from L1, not saturated).
//  (2) No barriers, no loop LDS: free-running waves de-phase, so one wave's
//      spine(VALU) overlaps another's PV(MFMA).
//  (3) exp2f spine (log2e folded into K at proj).
// Cost: spine duplicated across the c-half pair (VALU x~1.5 net).
// acc[2][4] f32x16 = 128 AGPR; launch_bounds(512,2) -> 2 waves/SIMD.
// ---------------------------------------------------------------------------
__global__ __launch_bounds__(512, 2) void attn_kernel(
    const __bf16* __restrict__ qkpk, const __bf16* __restrict__ vpk,
    __bf16* __restrict__ pO, float* __restrict__ Lp) {
  __shared__ __align__(16) char smem[135168];  // 8 waves x [128c][66i] bf16

  const int t = threadIdx.x;
  const int l = t & 63, w = t >> 6;          // 8 waves
  const int h = l >> 5, l31 = l & 31;

  const int bi = blockIdx.x;
  const int xcd = bi & 7;
  const int combo = xcd * 2 + ((bi >> 3) & 1);  // (b,jp) pinned to one XCD
  const int ig = bi >> 4;                       // 0..15
  const int b = combo >> 2, jp = combo & 3;
  const int ih = w >> 1, chalf = w & 1;         // i-range 0..3, c-half 0..1
  const int i0 = ig * 256 + ih * 64;            // wave's 64-row i base

  const __bf16* qkb = qkpk + (size_t)b * 262144;
  const __bf16* vpb = vpk + (size_t)b * 1048576;
  const int jq0 = jp << 10;

  // Q B-frags for the two i-tiles (lane = col = i), hoisted
  const __bf16* qpA = qkb + (size_t)(i0 >> 5) * 2048 + h * 256 + l31 * 8;
  const bf16x8 qA0 = *(const bf16x8*)(qpA);
  const bf16x8 qA1 = *(const bf16x8*)(qpA + 512);
  const bf16x8 qB0 = *(const bf16x8*)(qpA + 2048);
  const bf16x8 qB1 = *(const bf16x8*)(qpA + 2048 + 512);

  f32x16 acc[2][4] = {};   // [it][ct] -> c = chalf*128 + ct*32 + l31
  float rsA = 0.f, rsB = 0.f;

  const __bf16* kbase = qkb + 1024 + h * 256 + l31 * 8;   // K A-frag base
  const int vfo = h * 2048 + (chalf * 128 + l31) * 8;     // + ct*256

  bf16x8 kf0 = *(const bf16x8*)(kbase + (size_t)(jq0 >> 5) * 2048);
  bf16x8 kf1 = *(const bf16x8*)(kbase + (size_t)(jq0 >> 5) * 2048 + 512);

#pragma unroll 1
  for (int ch = 0; ch < 32; ++ch) {
    const __bf16* vchunk = vpb + (size_t)((jq0 >> 4) + ch * 2) * 4096 + vfo;
    // early-issue V ct=0 (L1 latency hides under the spine)
    bf16x8 va = *(const bf16x8*)(vchunk);
    bf16x8 vb_ = *(const bf16x8*)(vchunk + 4096);

    // spine: S^T = mfma(K,Q) for both i-tiles; lane holds P rows
    f32x16 s = {};
    s = mfma32(kf0, qA0, s);
    s = mfma32(kf1, qA1, s);
    f32x16 sB = {};
    sB = mfma32(kf0, qB0, sB);
    sB = mfma32(kf1, qB1, sB);

    // K prefetch for next chunk
    bf16x8 kn0, kn1;
    if (ch < 31) {
      const __bf16* kp = kbase + (size_t)((jq0 >> 5) + ch + 1) * 2048;
      kn0 = *(const bf16x8*)(kp);
      kn1 = *(const bf16x8*)(kp + 512);
    }

    // exp2 + rowsum + pack, tile A
    float p[16];
#pragma unroll
    for (int r = 0; r < 16; r++) { p[r] = exp2f(s[r]); rsA += p[r]; }
    unsigned int a0 = cvtpk(p[0], p[1]), a1 = cvtpk(p[2], p[3]);
    unsigned int a2 = cvtpk(p[4], p[5]), a3 = cvtpk(p[6], p[7]);
    swap32(a0, a2); swap32(a1, a3);
    unsigned int a4 = cvtpk(p[8], p[9]), a5 = cvtpk(p[10], p[11]);
    unsigned int a6 = cvtpk(p[12], p[13]), a7 = cvtpk(p[14], p[15]);
    swap32(a4, a6); swap32(a5, a7);
    union { unsigned int u[4]; bf16x8 v; } A0, A1;
    A0.u[0] = a0; A0.u[1] = a1; A0.u[2] = a2; A0.u[3] = a3;
    A1.u[0] = a4; A1.u[1] = a5; A1.u[2] = a6; A1.u[3] = a7;

    // tile B
#pragma unroll
    for (int r = 0; r < 16; r++) { p[r] = exp2f(sB[r]); rsB += p[r]; }
    unsigned int b0 = cvtpk(p[0], p[1]), b1 = cvtpk(p[2], p[3]);
    unsigned int b2 = cvtpk(p[4], p[5]), b3 = cvtpk(p[6], p[7]);
    swap32(b0, b2); swap32(b1, b3);
    unsigned int b4 = cvtpk(p[8], p[9]), b5 = cvtpk(p[10], p[11]);
    unsigned int b6 = cvtpk(p[12], p[13]), b7 = cvtpk(p[14], p[15]);
    swap32(b4, b6); swap32(b5, b7);
    union { unsigned int u[4]; bf16x8 v; } B0, B1;
    B0.u[0] = b0; B0.u[1] = b1; B0.u[2] = b2; B0.u[3] = b3;
    B1.u[0] = b4; B1.u[1] = b5; B1.u[2] = b6; B1.u[3] = b7;

    if (ch < 31) { kf0 = kn0; kf1 = kn1; }

    // PV: each V frag feeds BOTH i-tiles (2 MFMAs/read); dbuf ct+1 prefetch
#pragma unroll
    for (int ct = 0; ct < 4; ct++) {
      bf16x8 na, nb;
      if (ct < 3) {
        na = *(const bf16x8*)(vchunk + (ct + 1) * 256);
        nb = *(const bf16x8*)(vchunk + 4096 + (ct + 1) * 256);
      }
      acc[0][ct] = mfma32(A0.v, va, acc[0][ct]);
      acc[1][ct] = mfma32(B0.v, va, acc[1][ct]);
      acc[0][ct] = mfma32(A1.v, vb_, acc[0][ct]);
      acc[1][ct] = mfma32(B1.v, vb_, acc[1][ct]);
      if (ct < 3) { va = na; vb_ = nb; }
    }
  }

  // epilogue: per-wave LDS transpose slice [128 c][66 i] = 8448 elems/wave
  __bf16* stage = (__bf16*)smem + (size_t)w * 8448;
#pragma unroll
  for (int it = 0; it < 2; it++)
#pragma unroll
    for (int ct = 0; ct < 4; ct++) {
      int c0 = ct * 32 + l31;
#pragma unroll
      for (int r = 0; r < 16; r++) {
        int i_loc = it * 32 + (r & 3) + 8 * (r >> 2) + 4 * h;
        stage[c0 * 66 + i_loc] = (__bf16)acc[it][ct][r];
      }
    }
  asm volatile("s_waitcnt lgkmcnt(0)" ::: "memory");  // wave-local

  // coalesced pO store (u32 = 2 i)
  unsigned short* ob = (unsigned short*)pO + (size_t)(jp * 4 + b) * 1048576 +
                       (size_t)chalf * 128 * 4096 + i0;
  const unsigned short* su = (const unsigned short*)stage;
#pragma unroll 1
  for (int e = l; e < 4096; e += 64) {
    int c = e >> 5, i2 = (e & 31) * 2;
    unsigned int vv = *(const unsigned int*)(su + c * 66 + i2);
    *(unsigned int*)(ob + (size_t)c * 4096 + i2) = vv;
  }

  // rowsums (c-half pair computes identical sums -> only chalf==0 writes)
  float ra = rsA + __shfl_xor(rsA, 32);
  float rb = rsB + __shfl_xor(rsB, 32);
  if (chalf == 0 && l < 32) {
    float* lpb = Lp + (size_t)(jp * 4 + b) * 4096 + i0;
    lpb[l] = ra;
    lpb[32 + l] = rb;
  }
}

// ---------------------------------------------------------------------------
// K3: combine partials + normalize + residual.
// ---------------------------------------------------------------------------
__global__ __launch_bounds__(256) void norm_kernel(
    const float* __restrict__ x, const float* __restrict__ gamma_p,
    const __bf16* __restrict__ pO, const float* __restrict__ Lp,
    float* __restrict__ out) {
  const int bc = blockIdx.x;           // b = bc>>8, c = bc&255
  const int b = bc >> 8;
  const float gm = gamma_p[0];
  const float* xr = x + (size_t)bc * 4096;
  float* orow = out + (size_t)bc * 4096;
  const __bf16* pbase = pO + (size_t)bc * 4096;   // +jp*4194304
  const float* lbase = Lp + (size_t)b * 4096;     // +jp*16384

  for (int i0 = threadIdx.x * 4; i0 < 4096; i0 += 1024) {
    float4 xv = *(const float4*)(xr + i0);
    float s0 = 0.f, s1 = 0.f, s2 = 0.f, s3 = 0.f;
    float l0 = 0.f, l1 = 0.f, l2 = 0.f, l3 = 0.f;
#pragma unroll
    for (int jp = 0; jp < 4; jp++) {
      bf16x4 pv = *(const bf16x4*)(pbase + (size_t)jp * 4194304 + i0);
      s0 += (float)pv[0]; s1 += (float)pv[1]; s2 += (float)pv[2]; s3 += (float)pv[3];
      float4 lv = *(const float4*)(lbase + (size_t)jp * 16384 + i0);
      l0 += lv.x; l1 += lv.y; l2 += lv.z; l3 += lv.w;
    }
    float4 ov;
    ov.x = gm * s0 / l0 + xv.x;
    ov.y = gm * s1 / l1 + xv.y;
    ov.z = gm * s2 / l2 + xv.z;
    ov.w = gm * s3 / l3 + xv.w;
    *(float4*)(orow + i0) = ov;
  }
}

// ---------------------------------------------------------------------------
extern "C" void kernel_launch(void* const* d_in, const int* in_sizes, int n_in,
                              void* d_out, int out_size, void* d_ws, size_t ws_size,
                              hipStream_t stream) {
  const float* x   = (const float*)d_in[0];
  const float* Wf  = (const float*)d_in[1];
  const float* bfv = (const float*)d_in[2];
  const float* Wg  = (const float*)d_in[3];
  const float* bgv = (const float*)d_in[4];
  const float* Wh  = (const float*)d_in[5];
  const float* bhv = (const float*)d_in[6];
  const float* gm  = (const float*)d_in[7];
  float* out = (float*)d_out;

  char* ws = (char*)d_ws;
  __bf16* Wb   = (__bf16*)ws;                     //   160 KiB  @ 0
  __bf16* qkpk = (__bf16*)(ws + 262144);          //  2 MiB
  __bf16* vpk  = (__bf16*)(ws + 2359296);         //  8 MiB
  __bf16* pO   = (__bf16*)(ws + 10747904);        // 32 MiB
  float*  Lp   = (float*)(ws + 44302336);         // 256 KiB

  hipLaunchKernelGGL(wcvt_kernel, dim3(320), dim3(256), 0, stream, Wf, Wg, Wh, Wb);
  hipLaunchKernelGGL(proj_kernel, dim3(512), dim3(512), 0, stream,
                     x, bfv, bgv, bhv, Wb, qkpk, vpk);
  hipLaunchKernelGGL(attn_kernel, dim3(256), dim3(512), 0, stream,
                     qkpk, vpk, pO, Lp);
  hipLaunchKernelGGL(norm_kernel, dim3(1024), dim3(256), 0, stream,
                     x, gm, pO, Lp, out);
}

// Round 13
// 170.421 us; speedup vs baseline: 1.0448x; 1.0448x over previous
//
#include <hip/hip_runtime.h>

typedef __bf16 bf16x8 __attribute__((ext_vector_type(8)));
typedef __bf16 bf16x4 __attribute__((ext_vector_type(4)));
typedef float f32x4 __attribute__((ext_vector_type(4)));
typedef float f32x16 __attribute__((ext_vector_type(16)));

__device__ __forceinline__ f32x4 mfma16(bf16x8 a, bf16x8 b, f32x4 c) {
  return __builtin_amdgcn_mfma_f32_16x16x32_bf16(a, b, c, 0, 0, 0);
}
__device__ __forceinline__ f32x16 mfma32(bf16x8 a, bf16x8 b, f32x16 c) {
  return __builtin_amdgcn_mfma_f32_32x32x16_bf16(a, b, c, 0, 0, 0);
}

// pack 2 fp32 -> u32 of 2 bf16 (compiler fuses to v_cvt_pk_bf16_f32)
__device__ __forceinline__ unsigned int cvtpk(float a, float b) {
  union { __bf16 h[2]; unsigned int u; } r;
  r.h[0] = (__bf16)a; r.h[1] = (__bf16)b;
  return r.u;
}
// v_permlane32_swap_b32: exchange across the 32-lane halves
__device__ __forceinline__ void swap32(unsigned int &a, unsigned int &b) {
  asm("v_permlane32_swap_b32 %0, %1" : "+v"(a), "+v"(b));
}

// Barrier that does NOT drain vmcnt: LDS ops fenced (lgkmcnt(0)), global
// prefetches (K regs, V stage loads) stay in flight across it (T4/T14).
__device__ __forceinline__ void sync_lds() {
  asm volatile("s_waitcnt lgkmcnt(0)" ::: "memory");
  __builtin_amdgcn_s_barrier();
}

// exp2 + rowsum + cvt_pk/permlane pack: S^T f32x16 -> two PV A-fragments
__device__ __forceinline__ void pack_tile(const f32x16 s, float &rs,
                                          bf16x8 &A0v, bf16x8 &A1v) {
  float p[16];
#pragma unroll
  for (int r = 0; r < 16; r++) { p[r] = exp2f(s[r]); rs += p[r]; }
  unsigned int a0 = cvtpk(p[0], p[1]), a1 = cvtpk(p[2], p[3]);
  unsigned int a2 = cvtpk(p[4], p[5]), a3 = cvtpk(p[6], p[7]);
  swap32(a0, a2); swap32(a1, a3);
  unsigned int a4 = cvtpk(p[8], p[9]), a5 = cvtpk(p[10], p[11]);
  unsigned int a6 = cvtpk(p[12], p[13]), a7 = cvtpk(p[14], p[15]);
  swap32(a4, a6); swap32(a5, a7);
  union { unsigned int u[4]; bf16x8 v; } A0, A1;
  A0.u[0] = a0; A0.u[1] = a1; A0.u[2] = a2; A0.u[3] = a3;
  A1.u[0] = a4; A1.u[1] = a5; A1.u[2] = a6; A1.u[3] = a7;
  A0v = A0.v; A1v = A1.v;
}

// ---------------------------------------------------------------------------
// K0: convert Wf(32x256) | Wg(32x256) | Wh(256x256) fp32 -> Wb bf16 [320][256]
// ---------------------------------------------------------------------------
__global__ void wcvt_kernel(const float* __restrict__ Wf, const float* __restrict__ Wg,
                            const float* __restrict__ Wh, __bf16* __restrict__ Wb) {
  int i = blockIdx.x * 256 + threadIdx.x;  // 0..81919
  float v;
  if (i < 8192)       v = Wf[i];
  else if (i < 16384) v = Wg[i - 8192];
  else                v = Wh[i - 16384];
  Wb[i] = (__bf16)v;
}

// ---------------------------------------------------------------------------
// K1: projections.
//   o<64  -> QK_pk[b][nt(128)][qk(2)][frag(2)][h(2)][r(32)][e(8)] bf16
//   o>=64 -> V_pk[b][jc(256)][h(2)][c(256)][e(8)] bf16 (via LDS transpose)
// K features (o in [32,64)) scaled by log2(e) at store: attn uses raw exp2.
// ---------------------------------------------------------------------------
__global__ __launch_bounds__(512) void proj_kernel(
    const float* __restrict__ x, const float* __restrict__ bfv,
    const float* __restrict__ bgv, const float* __restrict__ bhv,
    const __bf16* __restrict__ Wb, __bf16* __restrict__ qkpk,
    __bf16* __restrict__ vpk) {
  __shared__ __align__(16) char smem[2560 + 18432];
  __bf16* xT = (__bf16*)smem;           // [32 n][40 c] bf16
  __bf16* ho = (__bf16*)(smem + 2560);  // [256 c][36 n] bf16

  const int t = threadIdx.x;
  const int l = t & 63, wg = t >> 6, q = l >> 4, l15 = l & 15;
  const int nh = wg & 1, oh = wg >> 1;   // oh 0..3
  const int bi = blockIdx.x;
  const int b = bi >> 7;
  const int nt = bi & 127;               // 32-row n tile
  const int n0 = nt << 5;

  const float* xb = x + (size_t)b * 256 * 4096;

  f32x4 acc[5];
#pragma unroll
  for (int i = 0; i < 5; i++) acc[i] = (f32x4){0.f, 0.f, 0.f, 0.f};

  const int c_rel = t >> 4;        // 0..31
  const int n2 = (t & 15) * 2;     // 0..30

#pragma unroll 1
  for (int kc = 0; kc < 8; kc++) {
    __syncthreads();
    float2 v = *(const float2*)(xb + (size_t)(kc * 32 + c_rel) * 4096 + n0 + n2);
    xT[(n2 + 0) * 40 + c_rel] = (__bf16)v.x;
    xT[(n2 + 1) * 40 + c_rel] = (__bf16)v.y;
    __syncthreads();
    bf16x8 af = *(const bf16x8*)(xT + (nh * 16 + l15) * 40 + q * 8);
    const __bf16* wp = Wb + (size_t)(oh * 80 + l15) * 256 + kc * 32 + q * 8;
#pragma unroll
    for (int ot = 0; ot < 5; ot++) {
      bf16x8 bfr = *(const bf16x8*)(wp + (size_t)ot * 16 * 256);
      acc[ot] = mfma16(af, bfr, acc[ot]);
    }
  }

#pragma unroll
  for (int ot = 0; ot < 5; ot++) {
    int o = oh * 80 + ot * 16 + l15;
    float bias = (o < 32) ? bfv[o] : (o < 64) ? bgv[o - 32] : bhv[o - 64];
    if (oh == 0 && ot < 4) {
      int qk = o >> 5, fr = (o >> 4) & 1, hh = (o >> 3) & 1, e = o & 7;
      size_t base = ((size_t)b * 128 + nt) * 2048 + qk * 1024 + fr * 512 + hh * 256;
      float sc = (o >= 32) ? 1.44269504089f : 1.0f;   // fold log2e into K
#pragma unroll
      for (int r = 0; r < 4; r++) {
        int n_rel = nh * 16 + q * 4 + r;
        qkpk[base + n_rel * 8 + e] = (__bf16)((acc[ot][r] + bias) * sc);
      }
    } else {
#pragma unroll
      for (int r = 0; r < 4; r++) {
        int n_rel = nh * 16 + q * 4 + r;
        ho[(o - 64) * 36 + n_rel] = (__bf16)(acc[ot][r] + bias);
      }
    }
  }
  __syncthreads();
  unsigned short* vpku = (unsigned short*)vpk + (size_t)b * 1048576;
  const unsigned short* hou = (const unsigned short*)ho;
  for (int e = t; e < 4096; e += 512) {
    int c = e >> 4, nn = (e & 15) * 2;
    int n = n0 + nn;
    int jc = n >> 4, hh = (n >> 3) & 1, ee = n & 7;
    unsigned int vv = *(const unsigned int*)(hou + c * 36 + nn);
    *(unsigned int*)(vpku + (((size_t)(jc * 2 + hh) * 256 + c) * 8 + ee)) = vv;
  }
}

// ---------------------------------------------------------------------------
// K2: fused attention — r11 tiling (32i x 256c/wave, V LDS-staged, P in
// regs), NEW: spine software-pipelined one chunk ahead (T15-style).
// R12 verdict: pipes ran in SEQUENCE (VALU 1174 + MFMA 1152 + LDS 1540 =
// 3900-cyc chunk) because each barrier-locked phase was single-pipe. Here
// iteration ch runs: spine-MFMA(ch+1) -> PV(ch) jc-lo (8 mfma) ->
// exp/pack(ch+1) VALU -> PV(ch) jc-hi (8 mfma) -> stage write -> barrier.
// exp/pack of ch+1 is independent of PV(ch), so VALU overlaps MFMA inside
// every phase; target chunk ~= max(pipes) ~= 1540 cyc.
// ---------------------------------------------------------------------------
__global__ __launch_bounds__(512, 2) void attn_kernel(
    const __bf16* __restrict__ qkpk, const __bf16* __restrict__ vpk,
    __bf16* __restrict__ pO, float* __restrict__ Lp) {
  // loop: [0,32768) = V dbuf 2 x 16KB; epilogue: 8 x 17408 B stage overlay
  __shared__ __align__(16) char smem[139264];
  __bf16* Vbuf = (__bf16*)smem;

  const int t = threadIdx.x;
  const int l = t & 63, w = t >> 6;          // 8 waves
  const int h = l >> 5, l31 = l & 31;

  const int bi = blockIdx.x;
  const int xcd = bi & 7;
  const int combo = xcd * 2 + ((bi >> 3) & 1);  // (b,jp) pinned to one XCD
  const int ig = bi >> 4;                       // 0..15
  const int b = combo >> 2, jp = combo & 3;
  const int ti = ig * 8 + w;                    // i-tile 0..127
  const int n0 = ti << 5;

  const __bf16* qkb = qkpk + (size_t)b * 262144;
  const __bf16* vpb = vpk + (size_t)b * 1048576;
  const int jq0 = jp << 10;

  // Q B-frag (lane = col = i), hoisted
  const __bf16* qp = qkb + (size_t)ti * 2048 + h * 256 + l31 * 8;
  const bf16x8 qf0 = *(const bf16x8*)(qp);
  const bf16x8 qf1 = *(const bf16x8*)(qp + 512);

  f32x16 acc[8] = {};                        // [ct] -> c = ct*32 + l31
  float rsum = 0.f;

  const __bf16* kbase = qkb + 1024 + h * 256 + l31 * 8;  // K A-frag base
  const int vfo = h * 2048 + l31 * 8;        // V frag offset within jc-half

  // ---- preloop: stage V(0); spine(0) -> A_cur; prefetch K(1) ----
  bf16x8 pac0, pac1;                         // A_cur fragments
  {
    const __bf16* src = vpb + (size_t)(jq0 >> 4) * 4096;
    bf16x8 sa = *(const bf16x8*)(src + t * 8);
    bf16x8 sc = *(const bf16x8*)(src + 4096 + t * 8);

    bf16x8 k0 = *(const bf16x8*)(kbase + (size_t)(jq0 >> 5) * 2048);
    bf16x8 k1 = *(const bf16x8*)(kbase + (size_t)(jq0 >> 5) * 2048 + 512);
    f32x16 s = {};
    s = mfma32(k0, qf0, s);
    s = mfma32(k1, qf1, s);
    pack_tile(s, rsum, pac0, pac1);

    *(bf16x8*)(Vbuf + t * 8) = sa;
    *(bf16x8*)(Vbuf + 4096 + t * 8) = sc;
  }
  bf16x8 kf0 = *(const bf16x8*)(kbase + (size_t)((jq0 >> 5) + 1) * 2048);
  bf16x8 kf1 = *(const bf16x8*)(kbase + (size_t)((jq0 >> 5) + 1) * 2048 + 512);
  sync_lds();

  // ---- main loop: 32 chunks of 32 j; spine runs one chunk ahead ----
#pragma unroll 1
  for (int ch = 0; ch < 32; ++ch) {
    // stage loads for V(ch+1) — written at bottom (T14)
    bf16x8 sv0, sv1;
    if (ch < 31) {
      const __bf16* src = vpb + (size_t)((jq0 >> 4) + (ch + 1) * 2) * 4096;
      sv0 = *(const bf16x8*)(src + t * 8);
      sv1 = *(const bf16x8*)(src + 4096 + t * 8);
    }

    // spine(ch+1): 2 mfma -> s_next (kf holds K(ch+1))
    f32x16 s_next = {};
    if (ch < 31) {
      s_next = mfma32(kf0, qf0, s_next);
      s_next = mfma32(kf1, qf1, s_next);
    }
    if (ch < 30) {  // prefetch K(ch+2)
      const __bf16* kp = kbase + (size_t)((jq0 >> 5) + ch + 2) * 2048;
      kf0 = *(const bf16x8*)(kp);
      kf1 = *(const bf16x8*)(kp + 512);
    }

    const __bf16* rb = Vbuf + (ch & 1) * 8192;

    // PV(ch) jc-lo: 8 mfma with A_cur lo
#pragma unroll
    for (int ct = 0; ct < 8; ct++) {
      bf16x8 vv = *(const bf16x8*)(rb + vfo + ct * 256);
      acc[ct] = mfma32(pac0, vv, acc[ct]);
    }

    // exp/pack(ch+1) on VALU — independent of PV(ch), overlaps MFMA
    bf16x8 pan0, pan1;
    if (ch < 31) pack_tile(s_next, rsum, pan0, pan1);

    // PV(ch) jc-hi: 8 mfma with A_cur hi
#pragma unroll
    for (int ct = 0; ct < 8; ct++) {
      bf16x8 vv = *(const bf16x8*)(rb + 4096 + vfo + ct * 256);
      acc[ct] = mfma32(pac1, vv, acc[ct]);
    }

    // roll P state; write stage -> other buffer; lgkm-only barrier
    if (ch < 31) {
      pac0 = pan0; pac1 = pan1;
      __bf16* wb = Vbuf + ((ch + 1) & 1) * 8192;
      *(bf16x8*)(wb + t * 8) = sv0;
      *(bf16x8*)(wb + 4096 + t * 8) = sv1;
    }
    sync_lds();
  }

  // epilogue: wave-local LDS transpose slice [256 c][34 i] = 8704 elems/wave
  __bf16* stage = (__bf16*)smem + (size_t)w * 8704;
#pragma unroll
  for (int ct = 0; ct < 8; ct++) {
    int c0 = ct * 32 + l31;
#pragma unroll
    for (int r = 0; r < 16; r++) {
      int i_loc = (r & 3) + 8 * (r >> 2) + 4 * h;
      stage[c0 * 34 + i_loc] = (__bf16)acc[ct][r];
    }
  }
  asm volatile("s_waitcnt lgkmcnt(0)" ::: "memory");  // wave-local

  // coalesced pO store (u32 = 2 i)
  unsigned short* ob = (unsigned short*)pO + (size_t)(jp * 4 + b) * 1048576 + n0;
  const unsigned short* su = (const unsigned short*)stage;
#pragma unroll 1
  for (int e = l; e < 4096; e += 64) {
    int c = e >> 4, i2 = (e & 15) * 2;
    unsigned int vv = *(const unsigned int*)(su + c * 34 + i2);
    *(unsigned int*)(ob + (size_t)c * 4096 + i2) = vv;
  }

  // rowsum: combine lane halves -> L[i = l31]
  rsum += __shfl_xor(rsum, 32);
  if (l < 32) Lp[(size_t)(jp * 4 + b) * 4096 + n0 + l] = rsum;
}

// ---------------------------------------------------------------------------
// K3: combine partials + normalize + residual.
// ---------------------------------------------------------------------------
__global__ __launch_bounds__(256) void norm_kernel(
    const float* __restrict__ x, const float* __restrict__ gamma_p,
    const __bf16* __restrict__ pO, const float* __restrict__ Lp,
    float* __restrict__ out) {
  const int bc = blockIdx.x;           // b = bc>>8, c = bc&255
  const int b = bc >> 8;
  const float gm = gamma_p[0];
  const float* xr = x + (size_t)bc * 4096;
  float* orow = out + (size_t)bc * 4096;
  const __bf16* pbase = pO + (size_t)bc * 4096;   // +jp*4194304
  const float* lbase = Lp + (size_t)b * 4096;     // +jp*16384

  for (int i0 = threadIdx.x * 4; i0 < 4096; i0 += 1024) {
    float4 xv = *(const float4*)(xr + i0);
    float s0 = 0.f, s1 = 0.f, s2 = 0.f, s3 = 0.f;
    float l0 = 0.f, l1 = 0.f, l2 = 0.f, l3 = 0.f;
#pragma unroll
    for (int jp = 0; jp < 4; jp++) {
      bf16x4 pv = *(const bf16x4*)(pbase + (size_t)jp * 4194304 + i0);
      s0 += (float)pv[0]; s1 += (float)pv[1]; s2 += (float)pv[2]; s3 += (float)pv[3];
      float4 lv = *(const float4*)(lbase + (size_t)jp * 16384 + i0);
      l0 += lv.x; l1 += lv.y; l2 += lv.z; l3 += lv.w;
    }
    float4 ov;
    ov.x = gm * s0 / l0 + xv.x;
    ov.y = gm * s1 / l1 + xv.y;
    ov.z = gm * s2 / l2 + xv.z;
    ov.w = gm * s3 / l3 + xv.w;
    *(float4*)(orow + i0) = ov;
  }
}

// ---------------------------------------------------------------------------
extern "C" void kernel_launch(void* const* d_in, const int* in_sizes, int n_in,
                              void* d_out, int out_size, void* d_ws, size_t ws_size,
                              hipStream_t stream) {
  const float* x   = (const float*)d_in[0];
  const float* Wf  = (const float*)d_in[1];
  const float* bfv = (const float*)d_in[2];
  const float* Wg  = (const float*)d_in[3];
  const float* bgv = (const float*)d_in[4];
  const float* Wh  = (const float*)d_in[5];
  const float* bhv = (const float*)d_in[6];
  const float* gm  = (const float*)d_in[7];
  float* out = (float*)d_out;

  char* ws = (char*)d_ws;
  __bf16* Wb   = (__bf16*)ws;                     //   160 KiB  @ 0
  __bf16* qkpk = (__bf16*)(ws + 262144);          //  2 MiB
  __bf16* vpk  = (__bf16*)(ws + 2359296);         //  8 MiB
  __bf16* pO   = (__bf16*)(ws + 10747904);        // 32 MiB
  float*  Lp   = (float*)(ws + 44302336);         // 256 KiB

  hipLaunchKernelGGL(wcvt_kernel, dim3(320), dim3(256), 0, stream, Wf, Wg, Wh, Wb);
  hipLaunchKernelGGL(proj_kernel, dim3(512), dim3(512), 0, stream,
                     x, bfv, bgv, bhv, Wb, qkpk, vpk);
  hipLaunchKernelGGL(attn_kernel, dim3(256), dim3(512), 0, stream,
                     qkpk, vpk, pO, Lp);
  hipLaunchKernelGGL(norm_kernel, dim3(1024), dim3(256), 0, stream,
                     x, gm, pO, Lp, out);
}